// Round 14
// baseline (182.380 us; speedup 1.0000x reference)
//
#include <hip/hip_runtime.h>
#include <hip/hip_bf16.h>
#include <math.h>

#define Bsz 2
#define Cch 48
#define Hh 64
#define Ww 64
#define Nn 4096

typedef __bf16 bf16;
typedef __attribute__((ext_vector_type(8))) __bf16 bf16x8;
typedef __attribute__((ext_vector_type(4))) float f32x4;

#define LOG2E 1.44269504088896340736f

__device__ __forceinline__ float fast_exp2(float x){
#if __has_builtin(__builtin_amdgcn_exp2f)
  return __builtin_amdgcn_exp2f(x);   // v_exp_f32, compiler-managed hazards
#else
  return exp2f(x);
#endif
}

// ---------------- K1: conv1x1 (pixel-per-thread) + fused rpe2 table ----------
// One thread = one pixel, ALL 48 outputs (weights LDS-staged): x read ONCE
// (1.6MB total vs 75MB), per-thread contiguous float4/bf16x8 stores (write
// requests /4 vs the old one-channel-per-block scatter). rpe2[t][px] packs
// two bf16 rows (x LOG2E pre-scaled) per dword, as before.
__global__ __launch_bounds__(64) void k_conv1x1(const float* __restrict__ in,
                          const float* __restrict__ Wt,
                          const float* __restrict__ bias, float* __restrict__ qnc,
                          bf16* __restrict__ qbf, float* __restrict__ xt,
                          const float* __restrict__ rpe,
                          unsigned* __restrict__ rpe2){
  if (blockIdx.x >= Bsz * 64){
    int y = blockIdx.x - Bsz * 64;           // t-index 0..192
    for (int j = threadIdx.x; j < 312; j += 64){
      int xcol = j - 48;
      float lo = 0.f, hi = 0.f;
      if (xcol >= 0 && xcol < 191){
        if (y >= 1 && y < 192) lo = rpe[(y - 1) * 191 + xcol] * LOG2E;
        if (y < 191)           hi = rpe[y * 191 + xcol] * LOG2E;
      }
      unsigned ulo = __builtin_bit_cast(unsigned short, (bf16)lo);
      unsigned uhi = __builtin_bit_cast(unsigned short, (bf16)hi);
      rpe2[y * 312 + j] = (uhi << 16) | ulo;
    }
    return;
  }
  __shared__ float wS[48][48];
  __shared__ float bS[48];
  int tid = threadIdx.x;
  for (int f = tid; f < 2304; f += 64) wS[f / 48][f % 48] = Wt[f];
  if (tid < 48) bS[tid] = bias[tid];
  __syncthreads();
  int b = blockIdx.x >> 6;                   // 64 blocks per batch
  int p = (blockIdx.x & 63) * 64 + tid;      // pixel
  float xv[48];
  const float* xp = in + (size_t)(b * Cch) * Nn + p;
  #pragma unroll
  for (int c = 0; c < 48; c++) xv[c] = xp[c * Nn];
  size_t base = ((size_t)(b * Nn + p)) * 48;
  #pragma unroll
  for (int og = 0; og < 12; og++)            // xt: 12 contiguous float4/thread
    *(float4*)(xt + base + og * 4) =
        make_float4(xv[og * 4], xv[og * 4 + 1], xv[og * 4 + 2], xv[og * 4 + 3]);
  bf16 qv[64];
  #pragma unroll
  for (int og = 0; og < 12; og++){
    float a[4];
    #pragma unroll
    for (int r = 0; r < 4; r++){
      int o = og * 4 + r;
      float acc = bS[o];
      #pragma unroll
      for (int c = 0; c < 48; c++) acc += wS[o][c] * xv[c];
      a[r] = acc;
      qv[o] = (bf16)acc;
    }
    *(float4*)(qnc + base + og * 4) = make_float4(a[0], a[1], a[2], a[3]);
  }
  #pragma unroll
  for (int o = 48; o < 64; o++) qv[o] = (bf16)0.f;
  size_t qb = ((size_t)(b * Nn + p)) * 64;
  #pragma unroll
  for (int v8 = 0; v8 < 8; v8++)
    *(bf16x8*)(qbf + qb + v8 * 8) = *(bf16x8*)&qv[v8 * 8];
}

// ---------------- K2': FUSED offset-pos + sample + k,v projection ------------
// K/V written in MFMA-FRAGMENT-MAJOR layouts (R13-proven):
//   kk2[b][n>>4][s=k/8 (8)][key=n&15 (16)][e=k&7 (8)]
//   vt2[b][n>>5][ct=c/16 (3)][chan=c&15 (16)][q=(n&31)/8 (4)][e=n&7 (8)]
__global__ __launch_bounds__(512) void k_pos_kv(const float* __restrict__ qnc,
                           const float* __restrict__ dww, const float* __restrict__ dwb,
                           const float* __restrict__ lng, const float* __restrict__ lnb,
                           const float* __restrict__ pww,
                           const float* __restrict__ xt,
                           const float* __restrict__ Wk, const float* __restrict__ bk,
                           const float* __restrict__ Wv, const float* __restrict__ bv,
                           bf16* __restrict__ kk2, bf16* __restrict__ vt2,
                           float2* __restrict__ axay){
  __shared__ float wkt[48][49];   // wkt[c][o] = Wk[o][c]
  __shared__ float wvt[48][49];
  __shared__ float rowb[8][48];
  int tid = threadIdx.x;
  for (int f = tid; f < 2304; f += 512){
    int o = f / 48, c = f - o * 48;
    wkt[c][o] = Wk[f];
    wvt[c][o] = Wv[f];
  }
  __syncthreads();
  int wv = tid >> 6, lane = tid & 63;
  int idx = blockIdx.x * 8 + wv;
  int b = idx >> 12;
  int n = idx & (Nn - 1);
  int yq = n >> 6, xq = n & 63;
  int c = lane;
  // ---- phase 1: offset/pos ----
  float t = 0.f;
  if (c < 48){
    t = dwb[c];
    #pragma unroll
    for (int ky = -1; ky <= 1; ky++){
      int yy = yq + ky;
      if (yy < 0 || yy >= Hh) continue;          // wave-uniform branch
      #pragma unroll
      for (int kx = -1; kx <= 1; kx++){
        int xx = xq + kx;
        if (xx < 0 || xx >= Ww) continue;        // wave-uniform branch
        t = fmaf(qnc[((size_t)(b * Nn + yy * Ww + xx)) * 48 + c],
                 dww[c * 9 + (ky + 1) * 3 + (kx + 1)], t);
      }
    }
  }
  float s = t;
  #pragma unroll
  for (int m = 1; m < 64; m <<= 1) s += __shfl_xor(s, m);
  float mean = s * (1.f / 48.f);
  float d = (c < 48) ? (t - mean) : 0.f;
  float v = d * d;
  #pragma unroll
  for (int m = 1; m < 64; m <<= 1) v += __shfl_xor(v, m);
  float rstd = rsqrtf(v * (1.f / 48.f) + 1e-5f);
  float p0 = 0.f, p1 = 0.f;
  if (c < 48){
    float u = (t - mean) * rstd * lng[c] + lnb[c];
    u = 0.5f * u * (1.f + erff(u * 0.70710678118654752f));   // exact gelu
    p0 = pww[c] * u;
    p1 = pww[48 + c] * u;
  }
  #pragma unroll
  for (int m = 1; m < 64; m <<= 1){ p0 += __shfl_xor(p0, m); p1 += __shfl_xor(p1, m); }
  // butterfly leaves full sums in every lane -> all lanes compute pos
  float py = tanhf(p0) * (2.f / 63.f) + ((0.5f + (float)yq) * (2.f / 63.f) - 1.f);
  float px = tanhf(p1) * (2.f / 63.f) + ((0.5f + (float)xq) * (2.f / 63.f) - 1.f);
  if (lane == 0) axay[idx] = make_float2(95.f - 47.5f * py, 95.f - 47.5f * px);
  // ---- phase 2: bilinear sample (pixel-major) + K/V projection ----
  float gx = (px + 1.f) * 0.5f * 63.f;
  float gy = (py + 1.f) * 0.5f * 63.f;
  float x0f = floorf(gx), y0f = floorf(gy);
  float wx = gx - x0f, wy = gy - y0f;
  int x0 = (int)x0f, y0 = (int)y0f, x1 = x0 + 1, y1 = y0 + 1;
  float w00 = (1.f - wy) * (1.f - wx), w01 = (1.f - wy) * wx;
  float w10 = wy * (1.f - wx),         w11 = wy * wx;
  bool vx0 = (x0 >= 0) && (x0 < Ww), vx1 = (x1 >= 0) && (x1 < Ww);
  bool vy0 = (y0 >= 0) && (y0 < Hh), vy1 = (y1 >= 0) && (y1 < Hh);
  if (!(vx0 && vy0)) w00 = 0.f;
  if (!(vx1 && vy0)) w01 = 0.f;
  if (!(vx0 && vy1)) w10 = 0.f;
  if (!(vx1 && vy1)) w11 = 0.f;
  int cx0 = min(max(x0, 0), Ww - 1), cx1 = min(max(x1, 0), Ww - 1);
  int cy0 = min(max(y0, 0), Hh - 1), cy1 = min(max(y1, 0), Hh - 1);
  int i00 = cy0 * Ww + cx0, i01 = cy0 * Ww + cx1;
  int i10 = cy1 * Ww + cx0, i11 = cy1 * Ww + cx1;
  if (c < 48){
    const float* t00 = xt + (size_t)(b * Nn + i00) * 48;
    const float* t01 = xt + (size_t)(b * Nn + i01) * 48;
    const float* t10 = xt + (size_t)(b * Nn + i10) * 48;
    const float* t11 = xt + (size_t)(b * Nn + i11) * 48;
    rowb[wv][c] = w00 * t00[c] + w01 * t01[c] + w10 * t10[c] + w11 * t11[c];
  }
  // same-wave LDS RAW: compiler inserts lgkmcnt; no barrier needed
  int o = lane;
  if (o < 48){
    float ka = bk[o], va = bv[o];
    #pragma unroll
    for (int cc = 0; cc < 48; cc++){
      float r = rowb[wv][cc];                 // broadcast
      ka = fmaf(wkt[cc][o], r, ka);           // conflict-free (pad 49)
      va = fmaf(wvt[cc][o], r, va);
    }
    // fragment-major K: [b][n>>4][o>>3][n&15][o&7]
    kk2[((((size_t)b * 256 + (n >> 4)) * 8 + (o >> 3)) * 16 + (n & 15)) * 8 + (o & 7)]
        = (bf16)ka;
    // fragment-major V: [b][n>>5][o>>4][o&15][(n>>3)&3][n&7]
    vt2[((size_t)b * 128 + (n >> 5)) * 1536 + (o >> 4) * 512 + (o & 15) * 32
        + ((n >> 3) & 3) * 8 + (n & 7)] = (bf16)va;
  }
  if (o < 16)   // K zero-pad slices s=6,7 (k=48..63)
    kk2[((((size_t)b * 256 + (n >> 4)) * 8 + 6 + (o >> 3)) * 16 + (n & 15)) * 8 + (o & 7)]
        = (bf16)0.f;
}

// ---------------- K4: FUSED attention (blocks 0..1023) + window attn (1024+) -
// deform path: R13-proven (fragment-major K/V, 54.4us). Untouched.
// win path: unchanged. LDS union 25.6KB.
__global__ __launch_bounds__(256, 5) void k_attn_win(const bf16* __restrict__ q_bf,
                                              const bf16* __restrict__ kk2,
                                              const bf16* __restrict__ vt2,
                                              const float2* __restrict__ axay,
                                              const unsigned* __restrict__ rpe2,
                                              float* __restrict__ o_part,
                                              float* __restrict__ s_part,
                                              const float* __restrict__ x,
                                              const float* __restrict__ iw,
                                              const float* __restrict__ ib,
                                              const float* __restrict__ bng,
                                              const float* __restrict__ bnb,
                                              const float* __restrict__ bnm,
                                              const float* __restrict__ bnv,
                                              float* __restrict__ wout){
  __shared__ __align__(16) char smem[25600];
  const int tid = threadIdx.x;
  const int wid = tid >> 6, lane = tid & 63;
  const int q16 = lane >> 4, l16 = lane & 15;

  if (blockIdx.x < 1024){
    // ================= deformable attention path =================
    float (*g)[26] = (float(*)[26])smem;                 // 13312
    float* axs  = (float*)(smem + 13312);                // 512 (stores axf)
    float* wy0s = (float*)(smem + 14336);                // 512
    float* wy1s = (float*)(smem + 14848);                // 512
    int*   pbs  = (int*)  (smem + 15360);                // 512
    bf16 (*ps)[136] = (bf16(*)[136])(smem + 16384);      // 4352 -> 20736

    const int b  = blockIdx.x >> 9;
    const int kp = (blockIdx.x >> 8) & 1;
    const int m0 = (blockIdx.x & 255) * 16;
    const int wn0 = wid * 32;

    const bf16* qb = q_bf + ((size_t)(b * Nn + m0 + l16)) * 64;
    bf16x8 qf0 = *(const bf16x8*)(qb + q16 * 8);
    bf16x8 qf1 = *(const bf16x8*)(qb + 32 + q16 * 8);

    const float qgy = (float)(m0 >> 6) * (2.f / 63.f) - 1.f;
    const float byq = 47.5f * qgy;              // gyr = ay + byq
    const float scale2 = 0.14433756729740643f * LOG2E;   // 48^-0.5 * log2e
    const float bx0 = 47.5f * ((float)(m0 & 63) * (2.f / 63.f) - 1.f);
    float bxr[4];
    #pragma unroll
    for (int r = 0; r < 4; r++){
      int mcol = (m0 & 63) + q16 * 4 + r;
      bxr[r] = 47.5f * ((float)mcol * (2.f / 63.f) - 1.f);
    }

    f32x4 oacc[3];
    #pragma unroll
    for (int ct = 0; ct < 3; ct++) oacc[ct] = (f32x4){0.f, 0.f, 0.f, 0.f};
    float s_runw[4] = {0.f, 0.f, 0.f, 0.f};   // per-THREAD partials (reduce at end)

    for (int chk = 0; chk < 16; chk++){
      const int n0 = kp * 2048 + chk * 128;
      // per-wave bilinear params: lane<32 handles key wn0+lane
      if (lane < 32){
        int n = wn0 + lane;
        float2 aa = axay[(size_t)b * Nn + n0 + n];  // (ay, ax)
        float gyr = aa.x + byq;
        float y0f = floorf(gyr);
        float wy = gyr - y0f;
        int y0 = (int)y0f, y1 = y0 + 1;
        wy0s[n] = ((unsigned)y0 < 191u) ? (1.f - wy) : 0.f;
        wy1s[n] = ((unsigned)y1 < 191u) ? wy : 0.f;
        int xlo = (int)floorf(aa.y + bx0);
        int t = min(max(y0 + 1, 0), 192);
        pbs[n] = t * 312 + xlo + 48;   // dword index into rpe2 (>=0, proved)
        axs[n] = aa.y - (float)xlo;    // axf (exact: <=22-bit result)
      }
      // g-build: wave's own 32 keys; one paired load serves both rows
      {
        int s = lane >> 5, jj = lane & 31;
        if (jj < 26){
          #pragma unroll
          for (int it = 0; it < 16; it++){
            int n = wn0 + it * 2 + s;
            unsigned u = rpe2[pbs[n] + jj];
            float lo = __builtin_bit_cast(float, u << 16);
            float hi = __builtin_bit_cast(float, u & 0xffff0000u);
            g[n][jj] = wy0s[n] * lo + wy1s[n] * hi;
          }
        }
      }
      // QK^T MFMA: fragment-major K — 4 contiguous 1KB wave-reads
      f32x4 s0 = (f32x4){0.f, 0.f, 0.f, 0.f};
      f32x4 s1 = (f32x4){0.f, 0.f, 0.f, 0.f};
      {
        const bf16* kbase = kk2 + (((size_t)b * 256 + ((n0 + wn0) >> 4)) << 10);
        bf16x8 b00 = *(const bf16x8*)(kbase + lane * 8);
        bf16x8 b01 = *(const bf16x8*)(kbase + 512 + lane * 8);
        bf16x8 b10 = *(const bf16x8*)(kbase + 1024 + lane * 8);
        bf16x8 b11 = *(const bf16x8*)(kbase + 1536 + lane * 8);
        s0 = __builtin_amdgcn_mfma_f32_16x16x32_bf16(qf0, b00, s0, 0, 0, 0);
        s0 = __builtin_amdgcn_mfma_f32_16x16x32_bf16(qf1, b01, s0, 0, 0, 0);
        s1 = __builtin_amdgcn_mfma_f32_16x16x32_bf16(qf0, b10, s1, 0, 0, 0);
        s1 = __builtin_amdgcn_mfma_f32_16x16x32_bf16(qf1, b11, s1, 0, 0, 0);
      }
      // branchless bias + exp2 (logits bounded; 2^x)
      #pragma unroll
      for (int nt = 0; nt < 2; nt++){
        int nl = wn0 + nt * 16 + l16;
        float axf = axs[nl];
        f32x4 sv = nt ? s1 : s0;
        #pragma unroll
        for (int r = 0; r < 4; r++){
          float gxr = axf + bxr[r];            // in [0, 23.7) (proved)
          int j0 = (int)gxr;                   // trunc == floor (gxr >= 0)
          float wx = gxr - (float)j0;
          float g0 = g[nl][j0], g1 = g[nl][j0 + 1];
          float bias = fmaf(wx, g1 - g0, g0);
          float e = fast_exp2(fmaf(sv[r], scale2, bias));
          s_runw[r] += e;
          ps[q16 * 4 + r][nl] = (bf16)e;
        }
      }
      // PV MFMA: A=ps (same-wave), fragment-major V — 3 contiguous 1KB reads
      {
        bf16x8 pa = *(const bf16x8*)&ps[l16][wn0 + q16 * 8];
        const bf16* vbase = vt2 + ((size_t)b * 128 + ((n0 + wn0) >> 5)) * 1536
                          + l16 * 32 + q16 * 8;
        #pragma unroll
        for (int ct = 0; ct < 3; ct++){
          bf16x8 vb = *(const bf16x8*)(vbase + ct * 512);
          oacc[ct] = __builtin_amdgcn_mfma_f32_16x16x32_bf16(pa, vb, oacc[ct], 0, 0, 0);
        }
      }
    }
    // deferred denominator reduce (once, not per chunk)
    #pragma unroll
    for (int r = 0; r < 4; r++){
      #pragma unroll
      for (int msk = 1; msk < 16; msk <<= 1)
        s_runw[r] += __shfl_xor(s_runw[r], msk);
    }
    // epilogue: cross-wave plain sums (scratch aliases g/axs)
    __syncthreads();
    float* ored = (float*)g;         // 64x48 f32 = 12288 <= 13312
    float* sred = axs;               // 64 floats
    #pragma unroll
    for (int ct = 0; ct < 3; ct++)
      #pragma unroll
      for (int r = 0; r < 4; r++)
        ored[(wid * 16 + q16 * 4 + r) * 48 + ct * 16 + l16] = oacc[ct][r];
    if (l16 == 0){
      #pragma unroll
      for (int r = 0; r < 4; r++) sred[wid * 16 + q16 * 4 + r] = s_runw[r];
    }
    __syncthreads();
    size_t obase = ((size_t)(b * 2 + kp) * Cch) * Nn;
    #pragma unroll
    for (int e = 0; e < 3; e++){
      int idx = tid + e * 256;         // 768 = 48c x 16m
      int c = idx >> 4, mm = idx & 15;
      float v = ored[mm * 48 + c] + ored[(16 + mm) * 48 + c]
              + ored[(32 + mm) * 48 + c] + ored[(48 + mm) * 48 + c];
      o_part[obase + (size_t)c * Nn + m0 + mm] = v;
    }
    if (tid < 16)
      s_part[(size_t)(b * 2 + kp) * Nn + m0 + tid] =
          sred[tid] + sred[16 + tid] + sred[32 + tid] + sred[48 + tid];
  } else {
    // ================= window attention path =================
    bf16 (*xs)[72]  = (bf16(*)[72])smem;                  // 9216 (later psw)
    bf16 (*wtt)[72] = (bf16(*)[72])(smem + 9216);         // 4608
    bf16 (*qs)[72]  = (bf16(*)[72])(smem + 13824);        // 9216
    bf16 (*vst)[72] = (bf16(*)[72])(smem + 23040);        // 2304
    float* bnsc = (float*)(smem + 25344);                 // 128
    float* bnsh = (float*)(smem + 25472);                 // 128 -> 25600
    bf16 (*psw)[72] = xs;   // overlay: xs dead after proj barrier

    int wb = blockIdx.x - 1024;
    int s = wb >> 7;
    int r7 = wb & 127;
    int b = r7 >> 6, wi = r7 & 63;
    for (int f = tid; f < 64 * 48; f += 256){
      int t = f & 63, c = f >> 6;
      int p = (s == 0) ? (((wi >> 3) * 8 + (t >> 3)) * 64 + (wi & 7) * 8 + (t & 7))
            : (s == 1) ? (t * 64 + wi) : (wi * 64 + t);
      xs[t][c] = (bf16)x[((size_t)(b * 48 + c)) * Nn + p];
    }
    for (int f = tid; f < 64 * 16; f += 256){
      int t = f >> 4, j = f & 15;
      xs[t][48 + j] = (bf16)0.f;
      qs[t][16 + j] = (bf16)0.f;
    }
    for (int f = tid; f < 32 * 64; f += 256){
      int o = f >> 6, c = f & 63;
      wtt[o][c] = (c < 48) ? (bf16)iw[(s * 32 + o) * 48 + c] : (bf16)0.f;
    }
    if (tid < 32){
      int ch = s * 32 + tid;
      float sc = bng[ch] * rsqrtf(bnv[ch] + 1e-5f);
      bnsc[tid] = sc;
      bnsh[tid] = (ib[ch] - bnm[ch]) * sc + bnb[ch];
    }
    __syncthreads();
    {
      bf16x8 a0 = *(const bf16x8*)&xs[wid * 16 + l16][q16 * 8];
      bf16x8 a1 = *(const bf16x8*)&xs[wid * 16 + l16][32 + q16 * 8];
      #pragma unroll
      for (int nt = 0; nt < 2; nt++){
        bf16x8 b0 = *(const bf16x8*)&wtt[nt * 16 + l16][q16 * 8];
        bf16x8 b1 = *(const bf16x8*)&wtt[nt * 16 + l16][32 + q16 * 8];
        f32x4 acc = (f32x4){0.f, 0.f, 0.f, 0.f};
        acc = __builtin_amdgcn_mfma_f32_16x16x32_bf16(a0, b0, acc, 0, 0, 0);
        acc = __builtin_amdgcn_mfma_f32_16x16x32_bf16(a1, b1, acc, 0, 0, 0);
        float scv = bnsc[nt * 16 + l16], shv = bnsh[nt * 16 + l16];
        #pragma unroll
        for (int r = 0; r < 4; r++){
          float v = fmaf(acc[r], scv, shv);
          int tok = wid * 16 + q16 * 4 + r;
          if (nt == 0) qs[tok][l16] = (bf16)v;       // C-layout: col=channel
          else         vst[l16][tok] = (bf16)v;      // transposed
        }
      }
    }
    __syncthreads();   // all waves done with xs -> safe to overlay psw
    f32x4 sreg[4];
    {
      bf16x8 aq = *(const bf16x8*)&qs[wid * 16 + l16][q16 * 8];
      #pragma unroll
      for (int nt = 0; nt < 4; nt++){
        bf16x8 bq = *(const bf16x8*)&qs[nt * 16 + l16][q16 * 8];
        f32x4 acc = (f32x4){0.f, 0.f, 0.f, 0.f};
        sreg[nt] = __builtin_amdgcn_mfma_f32_16x16x32_bf16(aq, bq, acc, 0, 0, 0);
      }
    }
    float rinv[4];
    #pragma unroll
    for (int r = 0; r < 4; r++){
      float mx = fmaxf(fmaxf(sreg[0][r], sreg[1][r]), fmaxf(sreg[2][r], sreg[3][r]));
      #pragma unroll
      for (int msk = 1; msk < 16; msk <<= 1) mx = fmaxf(mx, __shfl_xor(mx, msk));
      float sum = 0.f;
      #pragma unroll
      for (int nt = 0; nt < 4; nt++){
        float e = __expf(sreg[nt][r] - mx);
        sum += e;
        psw[wid * 16 + q16 * 4 + r][nt * 16 + l16] = (bf16)e;
      }
      #pragma unroll
      for (int msk = 1; msk < 16; msk <<= 1) sum += __shfl_xor(sum, msk);
      rinv[r] = 1.f / sum;
    }
    f32x4 oac = (f32x4){0.f, 0.f, 0.f, 0.f};
    {
      bf16x8 pa0 = *(const bf16x8*)&psw[wid * 16 + l16][q16 * 8];
      bf16x8 pa1 = *(const bf16x8*)&psw[wid * 16 + l16][32 + q16 * 8];
      bf16x8 vb0 = *(const bf16x8*)&vst[l16][q16 * 8];
      bf16x8 vb1 = *(const bf16x8*)&vst[l16][32 + q16 * 8];
      oac = __builtin_amdgcn_mfma_f32_16x16x32_bf16(pa0, vb0, oac, 0, 0, 0);
      oac = __builtin_amdgcn_mfma_f32_16x16x32_bf16(pa1, vb1, oac, 0, 0, 0);
    }
    #pragma unroll
    for (int r = 0; r < 4; r++){
      int tok = wid * 16 + q16 * 4 + r;
      int p = (s == 0) ? (((wi >> 3) * 8 + (tok >> 3)) * 64 + (wi & 7) * 8 + (tok & 7))
            : (s == 1) ? (tok * 64 + wi) : (wi * 64 + tok);
      wout[((size_t)(b * 48 + s * 16 + l16)) * Nn + p] = oac[r] * rinv[r];
    }
  }
}

// ---------------- K5: pout conv + split-K merge + 0.5/0.5 mix ----------------
__global__ void k_final(const float* __restrict__ win, const float* __restrict__ pw,
                        const float* __restrict__ pb, const float* __restrict__ o_part,
                        const float* __restrict__ s_part, float* __restrict__ out){
  int chunk = blockIdx.x & 15;
  int o = (blockIdx.x >> 4) % Cch;
  int b = blockIdx.x / (16 * Cch);
  int p = chunk * 256 + threadIdx.x;
  float acc = pb[o];
  const float* ip = win + (b * Cch) * Nn + p;
  const float* wp = pw + o * Cch;
  #pragma unroll
  for (int c = 0; c < Cch; c++) acc += wp[c] * ip[c * Nn];
  float sden = s_part[(size_t)(b * 2) * Nn + p] + s_part[(size_t)(b * 2 + 1) * Nn + p];
  float odv = (o_part[((size_t)(b * 2) * Cch + o) * Nn + p]
             + o_part[((size_t)(b * 2 + 1) * Cch + o) * Nn + p]) / sden;
  out[(b * Cch + o) * Nn + p] = 0.5f * acc + 0.5f * odv;
}

extern "C" void kernel_launch(void* const* d_in, const int* in_sizes, int n_in,
                              void* d_out, int out_size, void* d_ws, size_t ws_size,
                              hipStream_t stream){
  const float* x   = (const float*)d_in[0];
  const float* Wq  = (const float*)d_in[1];
  const float* bq  = (const float*)d_in[2];
  const float* dww = (const float*)d_in[3];
  const float* dwb = (const float*)d_in[4];
  const float* lng = (const float*)d_in[5];
  const float* lnb = (const float*)d_in[6];
  const float* pww = (const float*)d_in[7];
  const float* Wk  = (const float*)d_in[8];
  const float* bk  = (const float*)d_in[9];
  const float* Wv  = (const float*)d_in[10];
  const float* bv  = (const float*)d_in[11];
  const float* iw  = (const float*)d_in[12];
  const float* ib  = (const float*)d_in[13];
  const float* bng = (const float*)d_in[14];
  const float* bnb = (const float*)d_in[15];
  const float* bnm = (const float*)d_in[16];
  const float* bnv = (const float*)d_in[17];
  const float* pw  = (const float*)d_in[18];
  const float* pb  = (const float*)d_in[19];
  const float* rpe = (const float*)d_in[20];

  // Workspace (f32-slot offsets). qnc aliases o_part[0,393216): qnc dead after
  // k_pos_kv, o_part written later by k_attn_win.
  float*    ws     = (float*)d_ws;
  float*    qnc    = ws;                    // [0,       393216)  dead after K2'
  float*    o_part = ws;                    // [0,       786432)
  float2*   axay   = (float2*)(ws + 802816);// 8192 float2 -> [802816, 819200)
  float*    wout   = ws + 819200;           // (B,C,N)     [819200, 1212416)
  bf16*     q_bf   = (bf16*)(ws + 1212416); // 524288 bf16 -> [1212416,1474560)
  bf16*     kk2    = (bf16*)(ws + 1474560); // 524288 bf16 -> [1474560,1736704)
  bf16*     vt2    = (bf16*)(ws + 1736704); // 393216 bf16 -> [1736704,1933312)
  float*    s_part = ws + 1933312;          // [1933312,1949696)
  unsigned* rpe2   = (unsigned*)(ws + 1949696); // 60216 dwords -> [1949696,2009912)
  float*    x_t    = ws + 2009912;          // (B,N,48) f32 -> [2009912,2403128) = 9.6 MB
  float*    out    = (float*)d_out;

  k_conv1x1 <<<Bsz * 64 + 193, 64, 0, stream>>>(x, Wq, bq, qnc, q_bf, x_t,
                                                rpe, rpe2);
  k_pos_kv  <<<(Bsz * Nn) / 8, 512, 0, stream>>>(qnc, dww, dwb, lng, lnb, pww,
                                                 x_t, Wk, bk, Wv, bv,
                                                 kk2, vt2, axay);
  k_attn_win<<<Bsz * 512 + 384, 256, 0, stream>>>(q_bf, kk2, vt2, axay, rpe2,
                                                  o_part, s_part,
                                                  x, iw, ib, bng, bnb, bnm, bnv, wout);
  k_final   <<<Bsz * Cch * 16, 256, 0, stream>>>(wout, pw, pb, o_part,
                                                 s_part, out);
}

// Round 15
// 176.967 us; speedup vs baseline: 1.0306x; 1.0306x over previous
//
#include <hip/hip_runtime.h>
#include <hip/hip_bf16.h>
#include <math.h>

#define Bsz 2
#define Cch 48
#define Hh 64
#define Ww 64
#define Nn 4096

typedef __bf16 bf16;
typedef __attribute__((ext_vector_type(8))) __bf16 bf16x8;
typedef __attribute__((ext_vector_type(4))) float f32x4;

#define LOG2E 1.44269504088896340736f

__device__ __forceinline__ float fast_exp2(float x){
#if __has_builtin(__builtin_amdgcn_exp2f)
  return __builtin_amdgcn_exp2f(x);   // v_exp_f32, compiler-managed hazards
#else
  return exp2f(x);
#endif
}

// ---------------- K1: conv1x1 -> qnc + q_bf + x_t, + fused rpe2 table --------
// R13-proven channel-per-block structure (R14's pixel-per-thread 64-thread
// variant regressed: 128 waves on 256 CUs = no latency hiding).
__global__ void k_conv1x1(const float* __restrict__ in, const float* __restrict__ Wt,
                          const float* __restrict__ bias, float* __restrict__ qnc,
                          bf16* __restrict__ qbf, float* __restrict__ xt,
                          const float* __restrict__ rpe,
                          unsigned* __restrict__ rpe2){
  if (blockIdx.x >= Bsz * Cch * 16){
    int y = blockIdx.x - Bsz * Cch * 16;     // t-index 0..192
    for (int j = threadIdx.x; j < 312; j += 256){
      int xcol = j - 48;
      float lo = 0.f, hi = 0.f;
      if (xcol >= 0 && xcol < 191){
        if (y >= 1 && y < 192) lo = rpe[(y - 1) * 191 + xcol] * LOG2E;
        if (y < 191)           hi = rpe[y * 191 + xcol] * LOG2E;
      }
      unsigned ulo = __builtin_bit_cast(unsigned short, (bf16)lo);
      unsigned uhi = __builtin_bit_cast(unsigned short, (bf16)hi);
      rpe2[y * 312 + j] = (uhi << 16) | ulo;
    }
    return;
  }
  int chunk = blockIdx.x & 15;            // N/256 = 16 chunks
  int o = (blockIdx.x >> 4) % Cch;
  int b = blockIdx.x / (16 * Cch);
  int p = chunk * 256 + threadIdx.x;
  float acc = bias[o];
  const float* ip = in + (b * Cch) * Nn + p;
  const float* wp = Wt + o * Cch;
  #pragma unroll
  for (int c = 0; c < Cch; c++) acc += wp[c] * ip[c * Nn];
  qnc[((size_t)(b * Nn + p)) * 48 + o] = acc;
  xt [((size_t)(b * Nn + p)) * 48 + o] = ip[o * Nn];   // pixel-major x copy
  size_t qb = ((size_t)(b * Nn + p)) * 64;
  qbf[qb + o] = (bf16)acc;
  if (o < 16) qbf[qb + 48 + o] = (bf16)0.f;   // zero-pad k=48..63
}

// ---------------- K2': FUSED offset-pos + sample + k,v projection ------------
// K/V written in MFMA-FRAGMENT-MAJOR layouts (R13-proven):
//   kk2[b][n>>4][s=k/8 (8)][key=n&15 (16)][e=k&7 (8)]
//   vt2[b][n>>5][ct=c/16 (3)][chan=c&15 (16)][q=(n&31)/8 (4)][e=n&7 (8)]
__global__ __launch_bounds__(512) void k_pos_kv(const float* __restrict__ qnc,
                           const float* __restrict__ dww, const float* __restrict__ dwb,
                           const float* __restrict__ lng, const float* __restrict__ lnb,
                           const float* __restrict__ pww,
                           const float* __restrict__ xt,
                           const float* __restrict__ Wk, const float* __restrict__ bk,
                           const float* __restrict__ Wv, const float* __restrict__ bv,
                           bf16* __restrict__ kk2, bf16* __restrict__ vt2,
                           float2* __restrict__ axay){
  __shared__ float wkt[48][49];   // wkt[c][o] = Wk[o][c]
  __shared__ float wvt[48][49];
  __shared__ float rowb[8][48];
  int tid = threadIdx.x;
  for (int f = tid; f < 2304; f += 512){
    int o = f / 48, c = f - o * 48;
    wkt[c][o] = Wk[f];
    wvt[c][o] = Wv[f];
  }
  __syncthreads();
  int wv = tid >> 6, lane = tid & 63;
  int idx = blockIdx.x * 8 + wv;
  int b = idx >> 12;
  int n = idx & (Nn - 1);
  int yq = n >> 6, xq = n & 63;
  int c = lane;
  // ---- phase 1: offset/pos ----
  float t = 0.f;
  if (c < 48){
    t = dwb[c];
    #pragma unroll
    for (int ky = -1; ky <= 1; ky++){
      int yy = yq + ky;
      if (yy < 0 || yy >= Hh) continue;          // wave-uniform branch
      #pragma unroll
      for (int kx = -1; kx <= 1; kx++){
        int xx = xq + kx;
        if (xx < 0 || xx >= Ww) continue;        // wave-uniform branch
        t = fmaf(qnc[((size_t)(b * Nn + yy * Ww + xx)) * 48 + c],
                 dww[c * 9 + (ky + 1) * 3 + (kx + 1)], t);
      }
    }
  }
  float s = t;
  #pragma unroll
  for (int m = 1; m < 64; m <<= 1) s += __shfl_xor(s, m);
  float mean = s * (1.f / 48.f);
  float d = (c < 48) ? (t - mean) : 0.f;
  float v = d * d;
  #pragma unroll
  for (int m = 1; m < 64; m <<= 1) v += __shfl_xor(v, m);
  float rstd = rsqrtf(v * (1.f / 48.f) + 1e-5f);
  float p0 = 0.f, p1 = 0.f;
  if (c < 48){
    float u = (t - mean) * rstd * lng[c] + lnb[c];
    u = 0.5f * u * (1.f + erff(u * 0.70710678118654752f));   // exact gelu
    p0 = pww[c] * u;
    p1 = pww[48 + c] * u;
  }
  #pragma unroll
  for (int m = 1; m < 64; m <<= 1){ p0 += __shfl_xor(p0, m); p1 += __shfl_xor(p1, m); }
  // butterfly leaves full sums in every lane -> all lanes compute pos
  float py = tanhf(p0) * (2.f / 63.f) + ((0.5f + (float)yq) * (2.f / 63.f) - 1.f);
  float px = tanhf(p1) * (2.f / 63.f) + ((0.5f + (float)xq) * (2.f / 63.f) - 1.f);
  if (lane == 0) axay[idx] = make_float2(95.f - 47.5f * py, 95.f - 47.5f * px);
  // ---- phase 2: bilinear sample (pixel-major) + K/V projection ----
  float gx = (px + 1.f) * 0.5f * 63.f;
  float gy = (py + 1.f) * 0.5f * 63.f;
  float x0f = floorf(gx), y0f = floorf(gy);
  float wx = gx - x0f, wy = gy - y0f;
  int x0 = (int)x0f, y0 = (int)y0f, x1 = x0 + 1, y1 = y0 + 1;
  float w00 = (1.f - wy) * (1.f - wx), w01 = (1.f - wy) * wx;
  float w10 = wy * (1.f - wx),         w11 = wy * wx;
  bool vx0 = (x0 >= 0) && (x0 < Ww), vx1 = (x1 >= 0) && (x1 < Ww);
  bool vy0 = (y0 >= 0) && (y0 < Hh), vy1 = (y1 >= 0) && (y1 < Hh);
  if (!(vx0 && vy0)) w00 = 0.f;
  if (!(vx1 && vy0)) w01 = 0.f;
  if (!(vx0 && vy1)) w10 = 0.f;
  if (!(vx1 && vy1)) w11 = 0.f;
  int cx0 = min(max(x0, 0), Ww - 1), cx1 = min(max(x1, 0), Ww - 1);
  int cy0 = min(max(y0, 0), Hh - 1), cy1 = min(max(y1, 0), Hh - 1);
  int i00 = cy0 * Ww + cx0, i01 = cy0 * Ww + cx1;
  int i10 = cy1 * Ww + cx0, i11 = cy1 * Ww + cx1;
  if (c < 48){
    const float* t00 = xt + (size_t)(b * Nn + i00) * 48;
    const float* t01 = xt + (size_t)(b * Nn + i01) * 48;
    const float* t10 = xt + (size_t)(b * Nn + i10) * 48;
    const float* t11 = xt + (size_t)(b * Nn + i11) * 48;
    rowb[wv][c] = w00 * t00[c] + w01 * t01[c] + w10 * t10[c] + w11 * t11[c];
  }
  // same-wave LDS RAW: compiler inserts lgkmcnt; no barrier needed
  int o = lane;
  if (o < 48){
    float ka = bk[o], va = bv[o];
    #pragma unroll
    for (int cc = 0; cc < 48; cc++){
      float r = rowb[wv][cc];                 // broadcast
      ka = fmaf(wkt[cc][o], r, ka);           // conflict-free (pad 49)
      va = fmaf(wvt[cc][o], r, va);
    }
    // fragment-major K: [b][n>>4][o>>3][n&15][o&7]
    kk2[((((size_t)b * 256 + (n >> 4)) * 8 + (o >> 3)) * 16 + (n & 15)) * 8 + (o & 7)]
        = (bf16)ka;
    // fragment-major V: [b][n>>5][o>>4][o&15][(n>>3)&3][n&7]
    vt2[((size_t)b * 128 + (n >> 5)) * 1536 + (o >> 4) * 512 + (o & 15) * 32
        + ((n >> 3) & 3) * 8 + (n & 7)] = (bf16)va;
  }
  if (o < 16)   // K zero-pad slices s=6,7 (k=48..63)
    kk2[((((size_t)b * 256 + (n >> 4)) * 8 + 6 + (o >> 3)) * 16 + (n & 15)) * 8 + (o & 7)]
        = (bf16)0.f;
}

// ---------------- K4: FUSED attention (blocks 0..1023) + window attn (1024+) -
// deform path: R13-proven (fragment-major K/V, 54.4us). Untouched.
// win path: unchanged. LDS union 25.6KB.
__global__ __launch_bounds__(256, 5) void k_attn_win(const bf16* __restrict__ q_bf,
                                              const bf16* __restrict__ kk2,
                                              const bf16* __restrict__ vt2,
                                              const float2* __restrict__ axay,
                                              const unsigned* __restrict__ rpe2,
                                              float* __restrict__ o_part,
                                              float* __restrict__ s_part,
                                              const float* __restrict__ x,
                                              const float* __restrict__ iw,
                                              const float* __restrict__ ib,
                                              const float* __restrict__ bng,
                                              const float* __restrict__ bnb,
                                              const float* __restrict__ bnm,
                                              const float* __restrict__ bnv,
                                              float* __restrict__ wout){
  __shared__ __align__(16) char smem[25600];
  const int tid = threadIdx.x;
  const int wid = tid >> 6, lane = tid & 63;
  const int q16 = lane >> 4, l16 = lane & 15;

  if (blockIdx.x < 1024){
    // ================= deformable attention path =================
    float (*g)[26] = (float(*)[26])smem;                 // 13312
    float* axs  = (float*)(smem + 13312);                // 512 (stores axf)
    float* wy0s = (float*)(smem + 14336);                // 512
    float* wy1s = (float*)(smem + 14848);                // 512
    int*   pbs  = (int*)  (smem + 15360);                // 512
    bf16 (*ps)[136] = (bf16(*)[136])(smem + 16384);      // 4352 -> 20736

    const int b  = blockIdx.x >> 9;
    const int kp = (blockIdx.x >> 8) & 1;
    const int m0 = (blockIdx.x & 255) * 16;
    const int wn0 = wid * 32;

    const bf16* qb = q_bf + ((size_t)(b * Nn + m0 + l16)) * 64;
    bf16x8 qf0 = *(const bf16x8*)(qb + q16 * 8);
    bf16x8 qf1 = *(const bf16x8*)(qb + 32 + q16 * 8);

    const float qgy = (float)(m0 >> 6) * (2.f / 63.f) - 1.f;
    const float byq = 47.5f * qgy;              // gyr = ay + byq
    const float scale2 = 0.14433756729740643f * LOG2E;   // 48^-0.5 * log2e
    const float bx0 = 47.5f * ((float)(m0 & 63) * (2.f / 63.f) - 1.f);
    float bxr[4];
    #pragma unroll
    for (int r = 0; r < 4; r++){
      int mcol = (m0 & 63) + q16 * 4 + r;
      bxr[r] = 47.5f * ((float)mcol * (2.f / 63.f) - 1.f);
    }

    f32x4 oacc[3];
    #pragma unroll
    for (int ct = 0; ct < 3; ct++) oacc[ct] = (f32x4){0.f, 0.f, 0.f, 0.f};
    float s_runw[4] = {0.f, 0.f, 0.f, 0.f};   // per-THREAD partials (reduce at end)

    for (int chk = 0; chk < 16; chk++){
      const int n0 = kp * 2048 + chk * 128;
      // per-wave bilinear params: lane<32 handles key wn0+lane
      if (lane < 32){
        int n = wn0 + lane;
        float2 aa = axay[(size_t)b * Nn + n0 + n];  // (ay, ax)
        float gyr = aa.x + byq;
        float y0f = floorf(gyr);
        float wy = gyr - y0f;
        int y0 = (int)y0f, y1 = y0 + 1;
        wy0s[n] = ((unsigned)y0 < 191u) ? (1.f - wy) : 0.f;
        wy1s[n] = ((unsigned)y1 < 191u) ? wy : 0.f;
        int xlo = (int)floorf(aa.y + bx0);
        int t = min(max(y0 + 1, 0), 192);
        pbs[n] = t * 312 + xlo + 48;   // dword index into rpe2 (>=0, proved)
        axs[n] = aa.y - (float)xlo;    // axf (exact: <=22-bit result)
      }
      // g-build: wave's own 32 keys; one paired load serves both rows
      {
        int s = lane >> 5, jj = lane & 31;
        if (jj < 26){
          #pragma unroll
          for (int it = 0; it < 16; it++){
            int n = wn0 + it * 2 + s;
            unsigned u = rpe2[pbs[n] + jj];
            float lo = __builtin_bit_cast(float, u << 16);
            float hi = __builtin_bit_cast(float, u & 0xffff0000u);
            g[n][jj] = wy0s[n] * lo + wy1s[n] * hi;
          }
        }
      }
      // QK^T MFMA: fragment-major K — 4 contiguous 1KB wave-reads
      f32x4 s0 = (f32x4){0.f, 0.f, 0.f, 0.f};
      f32x4 s1 = (f32x4){0.f, 0.f, 0.f, 0.f};
      {
        const bf16* kbase = kk2 + (((size_t)b * 256 + ((n0 + wn0) >> 4)) << 10);
        bf16x8 b00 = *(const bf16x8*)(kbase + lane * 8);
        bf16x8 b01 = *(const bf16x8*)(kbase + 512 + lane * 8);
        bf16x8 b10 = *(const bf16x8*)(kbase + 1024 + lane * 8);
        bf16x8 b11 = *(const bf16x8*)(kbase + 1536 + lane * 8);
        s0 = __builtin_amdgcn_mfma_f32_16x16x32_bf16(qf0, b00, s0, 0, 0, 0);
        s0 = __builtin_amdgcn_mfma_f32_16x16x32_bf16(qf1, b01, s0, 0, 0, 0);
        s1 = __builtin_amdgcn_mfma_f32_16x16x32_bf16(qf0, b10, s1, 0, 0, 0);
        s1 = __builtin_amdgcn_mfma_f32_16x16x32_bf16(qf1, b11, s1, 0, 0, 0);
      }
      // branchless bias + exp2 (logits bounded; 2^x)
      #pragma unroll
      for (int nt = 0; nt < 2; nt++){
        int nl = wn0 + nt * 16 + l16;
        float axf = axs[nl];
        f32x4 sv = nt ? s1 : s0;
        #pragma unroll
        for (int r = 0; r < 4; r++){
          float gxr = axf + bxr[r];            // in [0, 23.7) (proved)
          int j0 = (int)gxr;                   // trunc == floor (gxr >= 0)
          float wx = gxr - (float)j0;
          float g0 = g[nl][j0], g1 = g[nl][j0 + 1];
          float bias = fmaf(wx, g1 - g0, g0);
          float e = fast_exp2(fmaf(sv[r], scale2, bias));
          s_runw[r] += e;
          ps[q16 * 4 + r][nl] = (bf16)e;
        }
      }
      // PV MFMA: A=ps (same-wave), fragment-major V — 3 contiguous 1KB reads
      {
        bf16x8 pa = *(const bf16x8*)&ps[l16][wn0 + q16 * 8];
        const bf16* vbase = vt2 + ((size_t)b * 128 + ((n0 + wn0) >> 5)) * 1536
                          + l16 * 32 + q16 * 8;
        #pragma unroll
        for (int ct = 0; ct < 3; ct++){
          bf16x8 vb = *(const bf16x8*)(vbase + ct * 512);
          oacc[ct] = __builtin_amdgcn_mfma_f32_16x16x32_bf16(pa, vb, oacc[ct], 0, 0, 0);
        }
      }
    }
    // deferred denominator reduce (once, not per chunk)
    #pragma unroll
    for (int r = 0; r < 4; r++){
      #pragma unroll
      for (int msk = 1; msk < 16; msk <<= 1)
        s_runw[r] += __shfl_xor(s_runw[r], msk);
    }
    // epilogue: cross-wave plain sums (scratch aliases g/axs)
    __syncthreads();
    float* ored = (float*)g;         // 64x48 f32 = 12288 <= 13312
    float* sred = axs;               // 64 floats
    #pragma unroll
    for (int ct = 0; ct < 3; ct++)
      #pragma unroll
      for (int r = 0; r < 4; r++)
        ored[(wid * 16 + q16 * 4 + r) * 48 + ct * 16 + l16] = oacc[ct][r];
    if (l16 == 0){
      #pragma unroll
      for (int r = 0; r < 4; r++) sred[wid * 16 + q16 * 4 + r] = s_runw[r];
    }
    __syncthreads();
    size_t obase = ((size_t)(b * 2 + kp) * Cch) * Nn;
    #pragma unroll
    for (int e = 0; e < 3; e++){
      int idx = tid + e * 256;         // 768 = 48c x 16m
      int c = idx >> 4, mm = idx & 15;
      float v = ored[mm * 48 + c] + ored[(16 + mm) * 48 + c]
              + ored[(32 + mm) * 48 + c] + ored[(48 + mm) * 48 + c];
      o_part[obase + (size_t)c * Nn + m0 + mm] = v;
    }
    if (tid < 16)
      s_part[(size_t)(b * 2 + kp) * Nn + m0 + tid] =
          sred[tid] + sred[16 + tid] + sred[32 + tid] + sred[48 + tid];
  } else {
    // ================= window attention path =================
    bf16 (*xs)[72]  = (bf16(*)[72])smem;                  // 9216 (later psw)
    bf16 (*wtt)[72] = (bf16(*)[72])(smem + 9216);         // 4608
    bf16 (*qs)[72]  = (bf16(*)[72])(smem + 13824);        // 9216
    bf16 (*vst)[72] = (bf16(*)[72])(smem + 23040);        // 2304
    float* bnsc = (float*)(smem + 25344);                 // 128
    float* bnsh = (float*)(smem + 25472);                 // 128 -> 25600
    bf16 (*psw)[72] = xs;   // overlay: xs dead after proj barrier

    int wb = blockIdx.x - 1024;
    int s = wb >> 7;
    int r7 = wb & 127;
    int b = r7 >> 6, wi = r7 & 63;
    for (int f = tid; f < 64 * 48; f += 256){
      int t = f & 63, c = f >> 6;
      int p = (s == 0) ? (((wi >> 3) * 8 + (t >> 3)) * 64 + (wi & 7) * 8 + (t & 7))
            : (s == 1) ? (t * 64 + wi) : (wi * 64 + t);
      xs[t][c] = (bf16)x[((size_t)(b * 48 + c)) * Nn + p];
    }
    for (int f = tid; f < 64 * 16; f += 256){
      int t = f >> 4, j = f & 15;
      xs[t][48 + j] = (bf16)0.f;
      qs[t][16 + j] = (bf16)0.f;
    }
    for (int f = tid; f < 32 * 64; f += 256){
      int o = f >> 6, c = f & 63;
      wtt[o][c] = (c < 48) ? (bf16)iw[(s * 32 + o) * 48 + c] : (bf16)0.f;
    }
    if (tid < 32){
      int ch = s * 32 + tid;
      float sc = bng[ch] * rsqrtf(bnv[ch] + 1e-5f);
      bnsc[tid] = sc;
      bnsh[tid] = (ib[ch] - bnm[ch]) * sc + bnb[ch];
    }
    __syncthreads();
    {
      bf16x8 a0 = *(const bf16x8*)&xs[wid * 16 + l16][q16 * 8];
      bf16x8 a1 = *(const bf16x8*)&xs[wid * 16 + l16][32 + q16 * 8];
      #pragma unroll
      for (int nt = 0; nt < 2; nt++){
        bf16x8 b0 = *(const bf16x8*)&wtt[nt * 16 + l16][q16 * 8];
        bf16x8 b1 = *(const bf16x8*)&wtt[nt * 16 + l16][32 + q16 * 8];
        f32x4 acc = (f32x4){0.f, 0.f, 0.f, 0.f};
        acc = __builtin_amdgcn_mfma_f32_16x16x32_bf16(a0, b0, acc, 0, 0, 0);
        acc = __builtin_amdgcn_mfma_f32_16x16x32_bf16(a1, b1, acc, 0, 0, 0);
        float scv = bnsc[nt * 16 + l16], shv = bnsh[nt * 16 + l16];
        #pragma unroll
        for (int r = 0; r < 4; r++){
          float v = fmaf(acc[r], scv, shv);
          int tok = wid * 16 + q16 * 4 + r;
          if (nt == 0) qs[tok][l16] = (bf16)v;       // C-layout: col=channel
          else         vst[l16][tok] = (bf16)v;      // transposed
        }
      }
    }
    __syncthreads();   // all waves done with xs -> safe to overlay psw
    f32x4 sreg[4];
    {
      bf16x8 aq = *(const bf16x8*)&qs[wid * 16 + l16][q16 * 8];
      #pragma unroll
      for (int nt = 0; nt < 4; nt++){
        bf16x8 bq = *(const bf16x8*)&qs[nt * 16 + l16][q16 * 8];
        f32x4 acc = (f32x4){0.f, 0.f, 0.f, 0.f};
        sreg[nt] = __builtin_amdgcn_mfma_f32_16x16x32_bf16(aq, bq, acc, 0, 0, 0);
      }
    }
    float rinv[4];
    #pragma unroll
    for (int r = 0; r < 4; r++){
      float mx = fmaxf(fmaxf(sreg[0][r], sreg[1][r]), fmaxf(sreg[2][r], sreg[3][r]));
      #pragma unroll
      for (int msk = 1; msk < 16; msk <<= 1) mx = fmaxf(mx, __shfl_xor(mx, msk));
      float sum = 0.f;
      #pragma unroll
      for (int nt = 0; nt < 4; nt++){
        float e = __expf(sreg[nt][r] - mx);
        sum += e;
        psw[wid * 16 + q16 * 4 + r][nt * 16 + l16] = (bf16)e;
      }
      #pragma unroll
      for (int msk = 1; msk < 16; msk <<= 1) sum += __shfl_xor(sum, msk);
      rinv[r] = 1.f / sum;
    }
    f32x4 oac = (f32x4){0.f, 0.f, 0.f, 0.f};
    {
      bf16x8 pa0 = *(const bf16x8*)&psw[wid * 16 + l16][q16 * 8];
      bf16x8 pa1 = *(const bf16x8*)&psw[wid * 16 + l16][32 + q16 * 8];
      bf16x8 vb0 = *(const bf16x8*)&vst[l16][q16 * 8];
      bf16x8 vb1 = *(const bf16x8*)&vst[l16][32 + q16 * 8];
      oac = __builtin_amdgcn_mfma_f32_16x16x32_bf16(pa0, vb0, oac, 0, 0, 0);
      oac = __builtin_amdgcn_mfma_f32_16x16x32_bf16(pa1, vb1, oac, 0, 0, 0);
    }
    #pragma unroll
    for (int r = 0; r < 4; r++){
      int tok = wid * 16 + q16 * 4 + r;
      int p = (s == 0) ? (((wi >> 3) * 8 + (tok >> 3)) * 64 + (wi & 7) * 8 + (tok & 7))
            : (s == 1) ? (tok * 64 + wi) : (wi * 64 + tok);
      wout[((size_t)(b * 48 + s * 16 + l16)) * Nn + p] = oac[r] * rinv[r];
    }
  }
}

// ---------------- K5: pout conv + split-K merge (request-optimized) ----------
// 128 blocks x 256 threads (4 waves — R14 lesson: keep >=4 waves/block).
// win tile 48x64 LDS-staged once (12 coalesced rounds): read requests
// ~350/block vs 3072/wave channel-major. Each thread: 1 pixel, 12 outputs.
// FMA order per output identical to original (c ascending); odv uses /sden.
__global__ __launch_bounds__(256) void k_final(const float* __restrict__ win,
                        const float* __restrict__ pw,
                        const float* __restrict__ pb, const float* __restrict__ o_part,
                        const float* __restrict__ s_part, float* __restrict__ out){
  __shared__ float winS[48][64];   // 12KB
  __shared__ float wS[48][48];     // 9KB
  __shared__ float bS[48];
  int tid = threadIdx.x;
  int b = blockIdx.x >> 6;
  int p0 = (blockIdx.x & 63) * 64;
  for (int f = tid; f < 2304; f += 256) wS[f / 48][f % 48] = pw[f];   // wS[o][c]
  if (tid < 48) bS[tid] = pb[tid];
  for (int f = tid; f < 3072; f += 256){
    int c = f >> 6, px = f & 63;
    winS[c][px] = win[((size_t)(b * 48 + c)) * Nn + p0 + px];
  }
  __syncthreads();
  int px = tid & 63, og = tid >> 6;        // og 0..3 (wave-uniform), 12 o each
  int p = p0 + px;
  float acc[12];
  #pragma unroll
  for (int r = 0; r < 12; r++) acc[r] = bS[og * 12 + r];
  #pragma unroll
  for (int c = 0; c < 48; c++){
    float wv = winS[c][px];                // conflict-free (consecutive lanes)
    #pragma unroll
    for (int r = 0; r < 12; r++)
      acc[r] = fmaf(wS[og * 12 + r][c], wv, acc[r]);   // broadcast weight
  }
  float sden = s_part[(size_t)(b * 2) * Nn + p] + s_part[(size_t)(b * 2 + 1) * Nn + p];
  #pragma unroll
  for (int r = 0; r < 12; r++){
    int o = og * 12 + r;
    float odv = (o_part[((size_t)(b * 2) * Cch + o) * Nn + p]
               + o_part[((size_t)(b * 2 + 1) * Cch + o) * Nn + p]) / sden;
    out[((size_t)(b * Cch + o)) * Nn + p] = 0.5f * acc[r] + 0.5f * odv;
  }
}

extern "C" void kernel_launch(void* const* d_in, const int* in_sizes, int n_in,
                              void* d_out, int out_size, void* d_ws, size_t ws_size,
                              hipStream_t stream){
  const float* x   = (const float*)d_in[0];
  const float* Wq  = (const float*)d_in[1];
  const float* bq  = (const float*)d_in[2];
  const float* dww = (const float*)d_in[3];
  const float* dwb = (const float*)d_in[4];
  const float* lng = (const float*)d_in[5];
  const float* lnb = (const float*)d_in[6];
  const float* pww = (const float*)d_in[7];
  const float* Wk  = (const float*)d_in[8];
  const float* bk  = (const float*)d_in[9];
  const float* Wv  = (const float*)d_in[10];
  const float* bv  = (const float*)d_in[11];
  const float* iw  = (const float*)d_in[12];
  const float* ib  = (const float*)d_in[13];
  const float* bng = (const float*)d_in[14];
  const float* bnb = (const float*)d_in[15];
  const float* bnm = (const float*)d_in[16];
  const float* bnv = (const float*)d_in[17];
  const float* pw  = (const float*)d_in[18];
  const float* pb  = (const float*)d_in[19];
  const float* rpe = (const float*)d_in[20];

  // Workspace (f32-slot offsets). qnc aliases o_part[0,393216): qnc dead after
  // k_pos_kv, o_part written later by k_attn_win.
  float*    ws     = (float*)d_ws;
  float*    qnc    = ws;                    // [0,       393216)  dead after K2'
  float*    o_part = ws;                    // [0,       786432)
  float2*   axay   = (float2*)(ws + 802816);// 8192 float2 -> [802816, 819200)
  float*    wout   = ws + 819200;           // (B,C,N)     [819200, 1212416)
  bf16*     q_bf   = (bf16*)(ws + 1212416); // 524288 bf16 -> [1212416,1474560)
  bf16*     kk2    = (bf16*)(ws + 1474560); // 524288 bf16 -> [1474560,1736704)
  bf16*     vt2    = (bf16*)(ws + 1736704); // 393216 bf16 -> [1736704,1933312)
  float*    s_part = ws + 1933312;          // [1933312,1949696)
  unsigned* rpe2   = (unsigned*)(ws + 1949696); // 60216 dwords -> [1949696,2009912)
  float*    x_t    = ws + 2009912;          // (B,N,48) f32 -> [2009912,2403128) = 9.6 MB
  float*    out    = (float*)d_out;

  k_conv1x1 <<<Bsz * Cch * 16 + 193, 256, 0, stream>>>(x, Wq, bq, qnc, q_bf, x_t,
                                                       rpe, rpe2);
  k_pos_kv  <<<(Bsz * Nn) / 8, 512, 0, stream>>>(qnc, dww, dwb, lng, lnb, pww,
                                                 x_t, Wk, bk, Wv, bv,
                                                 kk2, vt2, axay);
  k_attn_win<<<Bsz * 512 + 384, 256, 0, stream>>>(q_bf, kk2, vt2, axay, rpe2,
                                                  o_part, s_part,
                                                  x, iw, ib, bng, bnb, bnm, bnv, wout);
  k_final   <<<Bsz * 64, 256, 0, stream>>>(wout, pw, pb, o_part,
                                           s_part, out);
}

// Round 16
// 167.594 us; speedup vs baseline: 1.0882x; 1.0559x over previous
//
#include <hip/hip_runtime.h>
#include <hip/hip_bf16.h>
#include <math.h>

#define Bsz 2
#define Cch 48
#define Hh 64
#define Ww 64
#define Nn 4096

typedef __bf16 bf16;
typedef __attribute__((ext_vector_type(8))) __bf16 bf16x8;
typedef __attribute__((ext_vector_type(4))) float f32x4;

#define LOG2E 1.44269504088896340736f

__device__ __forceinline__ float fast_exp2(float x){
#if __has_builtin(__builtin_amdgcn_exp2f)
  return __builtin_amdgcn_exp2f(x);   // v_exp_f32, compiler-managed hazards
#else
  return exp2f(x);
#endif
}

// ---------------- K1: conv1x1 -> qnc + q_bf + x_t, + fused rpe2 table --------
// rpe2[t][px] packs two bf16 rows (x LOG2E pre-scaled) in one dword.
// x_t[b][p][c] = x[b][c][p] (pixel-major copy). Channel-per-block structure:
// R14/R15 proved the "request-optimized" small-kernel variants regress —
// these kernels are launch/ramp-bound; max block count wins, L2 absorbs reuse.
__global__ void k_conv1x1(const float* __restrict__ in, const float* __restrict__ Wt,
                          const float* __restrict__ bias, float* __restrict__ qnc,
                          bf16* __restrict__ qbf, float* __restrict__ xt,
                          const float* __restrict__ rpe,
                          unsigned* __restrict__ rpe2){
  if (blockIdx.x >= Bsz * Cch * 16){
    int y = blockIdx.x - Bsz * Cch * 16;     // t-index 0..192
    for (int j = threadIdx.x; j < 312; j += 256){
      int xcol = j - 48;
      float lo = 0.f, hi = 0.f;
      if (xcol >= 0 && xcol < 191){
        if (y >= 1 && y < 192) lo = rpe[(y - 1) * 191 + xcol] * LOG2E;
        if (y < 191)           hi = rpe[y * 191 + xcol] * LOG2E;
      }
      unsigned ulo = __builtin_bit_cast(unsigned short, (bf16)lo);
      unsigned uhi = __builtin_bit_cast(unsigned short, (bf16)hi);
      rpe2[y * 312 + j] = (uhi << 16) | ulo;
    }
    return;
  }
  int chunk = blockIdx.x & 15;            // N/256 = 16 chunks
  int o = (blockIdx.x >> 4) % Cch;
  int b = blockIdx.x / (16 * Cch);
  int p = chunk * 256 + threadIdx.x;
  float acc = bias[o];
  const float* ip = in + (b * Cch) * Nn + p;
  const float* wp = Wt + o * Cch;
  #pragma unroll
  for (int c = 0; c < Cch; c++) acc += wp[c] * ip[c * Nn];
  qnc[((size_t)(b * Nn + p)) * 48 + o] = acc;
  xt [((size_t)(b * Nn + p)) * 48 + o] = ip[o * Nn];   // pixel-major x copy
  size_t qb = ((size_t)(b * Nn + p)) * 64;
  qbf[qb + o] = (bf16)acc;
  if (o < 16) qbf[qb + 48 + o] = (bf16)0.f;   // zero-pad k=48..63
}

// ---------------- K2': FUSED offset-pos + sample + k,v projection ------------
// K/V written in MFMA-FRAGMENT-MAJOR layouts (R13-proven):
//   kk2[b][n>>4][s=k/8 (8)][key=n&15 (16)][e=k&7 (8)]
//   vt2[b][n>>5][ct=c/16 (3)][chan=c&15 (16)][q=(n&31)/8 (4)][e=n&7 (8)]
__global__ __launch_bounds__(512) void k_pos_kv(const float* __restrict__ qnc,
                           const float* __restrict__ dww, const float* __restrict__ dwb,
                           const float* __restrict__ lng, const float* __restrict__ lnb,
                           const float* __restrict__ pww,
                           const float* __restrict__ xt,
                           const float* __restrict__ Wk, const float* __restrict__ bk,
                           const float* __restrict__ Wv, const float* __restrict__ bv,
                           bf16* __restrict__ kk2, bf16* __restrict__ vt2,
                           float2* __restrict__ axay){
  __shared__ float wkt[48][49];   // wkt[c][o] = Wk[o][c]
  __shared__ float wvt[48][49];
  __shared__ float rowb[8][48];
  int tid = threadIdx.x;
  for (int f = tid; f < 2304; f += 512){
    int o = f / 48, c = f - o * 48;
    wkt[c][o] = Wk[f];
    wvt[c][o] = Wv[f];
  }
  __syncthreads();
  int wv = tid >> 6, lane = tid & 63;
  int idx = blockIdx.x * 8 + wv;
  int b = idx >> 12;
  int n = idx & (Nn - 1);
  int yq = n >> 6, xq = n & 63;
  int c = lane;
  // ---- phase 1: offset/pos ----
  float t = 0.f;
  if (c < 48){
    t = dwb[c];
    #pragma unroll
    for (int ky = -1; ky <= 1; ky++){
      int yy = yq + ky;
      if (yy < 0 || yy >= Hh) continue;          // wave-uniform branch
      #pragma unroll
      for (int kx = -1; kx <= 1; kx++){
        int xx = xq + kx;
        if (xx < 0 || xx >= Ww) continue;        // wave-uniform branch
        t = fmaf(qnc[((size_t)(b * Nn + yy * Ww + xx)) * 48 + c],
                 dww[c * 9 + (ky + 1) * 3 + (kx + 1)], t);
      }
    }
  }
  float s = t;
  #pragma unroll
  for (int m = 1; m < 64; m <<= 1) s += __shfl_xor(s, m);
  float mean = s * (1.f / 48.f);
  float d = (c < 48) ? (t - mean) : 0.f;
  float v = d * d;
  #pragma unroll
  for (int m = 1; m < 64; m <<= 1) v += __shfl_xor(v, m);
  float rstd = rsqrtf(v * (1.f / 48.f) + 1e-5f);
  float p0 = 0.f, p1 = 0.f;
  if (c < 48){
    float u = (t - mean) * rstd * lng[c] + lnb[c];
    u = 0.5f * u * (1.f + erff(u * 0.70710678118654752f));   // exact gelu
    p0 = pww[c] * u;
    p1 = pww[48 + c] * u;
  }
  #pragma unroll
  for (int m = 1; m < 64; m <<= 1){ p0 += __shfl_xor(p0, m); p1 += __shfl_xor(p1, m); }
  // butterfly leaves full sums in every lane -> all lanes compute pos
  float py = tanhf(p0) * (2.f / 63.f) + ((0.5f + (float)yq) * (2.f / 63.f) - 1.f);
  float px = tanhf(p1) * (2.f / 63.f) + ((0.5f + (float)xq) * (2.f / 63.f) - 1.f);
  if (lane == 0) axay[idx] = make_float2(95.f - 47.5f * py, 95.f - 47.5f * px);
  // ---- phase 2: bilinear sample (pixel-major) + K/V projection ----
  float gx = (px + 1.f) * 0.5f * 63.f;
  float gy = (py + 1.f) * 0.5f * 63.f;
  float x0f = floorf(gx), y0f = floorf(gy);
  float wx = gx - x0f, wy = gy - y0f;
  int x0 = (int)x0f, y0 = (int)y0f, x1 = x0 + 1, y1 = y0 + 1;
  float w00 = (1.f - wy) * (1.f - wx), w01 = (1.f - wy) * wx;
  float w10 = wy * (1.f - wx),         w11 = wy * wx;
  bool vx0 = (x0 >= 0) && (x0 < Ww), vx1 = (x1 >= 0) && (x1 < Ww);
  bool vy0 = (y0 >= 0) && (y0 < Hh), vy1 = (y1 >= 0) && (y1 < Hh);
  if (!(vx0 && vy0)) w00 = 0.f;
  if (!(vx1 && vy0)) w01 = 0.f;
  if (!(vx0 && vy1)) w10 = 0.f;
  if (!(vx1 && vy1)) w11 = 0.f;
  int cx0 = min(max(x0, 0), Ww - 1), cx1 = min(max(x1, 0), Ww - 1);
  int cy0 = min(max(y0, 0), Hh - 1), cy1 = min(max(y1, 0), Hh - 1);
  int i00 = cy0 * Ww + cx0, i01 = cy0 * Ww + cx1;
  int i10 = cy1 * Ww + cx0, i11 = cy1 * Ww + cx1;
  if (c < 48){
    const float* t00 = xt + (size_t)(b * Nn + i00) * 48;
    const float* t01 = xt + (size_t)(b * Nn + i01) * 48;
    const float* t10 = xt + (size_t)(b * Nn + i10) * 48;
    const float* t11 = xt + (size_t)(b * Nn + i11) * 48;
    rowb[wv][c] = w00 * t00[c] + w01 * t01[c] + w10 * t10[c] + w11 * t11[c];
  }
  // same-wave LDS RAW: compiler inserts lgkmcnt; no barrier needed
  int o = lane;
  if (o < 48){
    float ka = bk[o], va = bv[o];
    #pragma unroll
    for (int cc = 0; cc < 48; cc++){
      float r = rowb[wv][cc];                 // broadcast
      ka = fmaf(wkt[cc][o], r, ka);           // conflict-free (pad 49)
      va = fmaf(wvt[cc][o], r, va);
    }
    // fragment-major K: [b][n>>4][o>>3][n&15][o&7]
    kk2[((((size_t)b * 256 + (n >> 4)) * 8 + (o >> 3)) * 16 + (n & 15)) * 8 + (o & 7)]
        = (bf16)ka;
    // fragment-major V: [b][n>>5][o>>4][o&15][(n>>3)&3][n&7]
    vt2[((size_t)b * 128 + (n >> 5)) * 1536 + (o >> 4) * 512 + (o & 15) * 32
        + ((n >> 3) & 3) * 8 + (n & 7)] = (bf16)va;
  }
  if (o < 16)   // K zero-pad slices s=6,7 (k=48..63)
    kk2[((((size_t)b * 256 + (n >> 4)) * 8 + 6 + (o >> 3)) * 16 + (n & 15)) * 8 + (o & 7)]
        = (bf16)0.f;
}

// ---------------- K4: FUSED attention (blocks 0..1023) + window attn (1024+) -
// deform path: R13-proven (fragment-major K/V, 54.4us). Untouched.
// win path: unchanged. LDS union 25.6KB.
__global__ __launch_bounds__(256, 5) void k_attn_win(const bf16* __restrict__ q_bf,
                                              const bf16* __restrict__ kk2,
                                              const bf16* __restrict__ vt2,
                                              const float2* __restrict__ axay,
                                              const unsigned* __restrict__ rpe2,
                                              float* __restrict__ o_part,
                                              float* __restrict__ s_part,
                                              const float* __restrict__ x,
                                              const float* __restrict__ iw,
                                              const float* __restrict__ ib,
                                              const float* __restrict__ bng,
                                              const float* __restrict__ bnb,
                                              const float* __restrict__ bnm,
                                              const float* __restrict__ bnv,
                                              float* __restrict__ wout){
  __shared__ __align__(16) char smem[25600];
  const int tid = threadIdx.x;
  const int wid = tid >> 6, lane = tid & 63;
  const int q16 = lane >> 4, l16 = lane & 15;

  if (blockIdx.x < 1024){
    // ================= deformable attention path =================
    float (*g)[26] = (float(*)[26])smem;                 // 13312
    float* axs  = (float*)(smem + 13312);                // 512 (stores axf)
    float* wy0s = (float*)(smem + 14336);                // 512
    float* wy1s = (float*)(smem + 14848);                // 512
    int*   pbs  = (int*)  (smem + 15360);                // 512
    bf16 (*ps)[136] = (bf16(*)[136])(smem + 16384);      // 4352 -> 20736

    const int b  = blockIdx.x >> 9;
    const int kp = (blockIdx.x >> 8) & 1;
    const int m0 = (blockIdx.x & 255) * 16;
    const int wn0 = wid * 32;

    const bf16* qb = q_bf + ((size_t)(b * Nn + m0 + l16)) * 64;
    bf16x8 qf0 = *(const bf16x8*)(qb + q16 * 8);
    bf16x8 qf1 = *(const bf16x8*)(qb + 32 + q16 * 8);

    const float qgy = (float)(m0 >> 6) * (2.f / 63.f) - 1.f;
    const float byq = 47.5f * qgy;              // gyr = ay + byq
    const float scale2 = 0.14433756729740643f * LOG2E;   // 48^-0.5 * log2e
    const float bx0 = 47.5f * ((float)(m0 & 63) * (2.f / 63.f) - 1.f);
    float bxr[4];
    #pragma unroll
    for (int r = 0; r < 4; r++){
      int mcol = (m0 & 63) + q16 * 4 + r;
      bxr[r] = 47.5f * ((float)mcol * (2.f / 63.f) - 1.f);
    }

    f32x4 oacc[3];
    #pragma unroll
    for (int ct = 0; ct < 3; ct++) oacc[ct] = (f32x4){0.f, 0.f, 0.f, 0.f};
    float s_runw[4] = {0.f, 0.f, 0.f, 0.f};   // per-THREAD partials (reduce at end)

    for (int chk = 0; chk < 16; chk++){
      const int n0 = kp * 2048 + chk * 128;
      // per-wave bilinear params: lane<32 handles key wn0+lane
      if (lane < 32){
        int n = wn0 + lane;
        float2 aa = axay[(size_t)b * Nn + n0 + n];  // (ay, ax)
        float gyr = aa.x + byq;
        float y0f = floorf(gyr);
        float wy = gyr - y0f;
        int y0 = (int)y0f, y1 = y0 + 1;
        wy0s[n] = ((unsigned)y0 < 191u) ? (1.f - wy) : 0.f;
        wy1s[n] = ((unsigned)y1 < 191u) ? wy : 0.f;
        int xlo = (int)floorf(aa.y + bx0);
        int t = min(max(y0 + 1, 0), 192);
        pbs[n] = t * 312 + xlo + 48;   // dword index into rpe2 (>=0, proved)
        axs[n] = aa.y - (float)xlo;    // axf (exact: <=22-bit result)
      }
      // g-build: wave's own 32 keys; one paired load serves both rows
      {
        int s = lane >> 5, jj = lane & 31;
        if (jj < 26){
          #pragma unroll
          for (int it = 0; it < 16; it++){
            int n = wn0 + it * 2 + s;
            unsigned u = rpe2[pbs[n] + jj];
            float lo = __builtin_bit_cast(float, u << 16);
            float hi = __builtin_bit_cast(float, u & 0xffff0000u);
            g[n][jj] = wy0s[n] * lo + wy1s[n] * hi;
          }
        }
      }
      // QK^T MFMA: fragment-major K — 4 contiguous 1KB wave-reads
      f32x4 s0 = (f32x4){0.f, 0.f, 0.f, 0.f};
      f32x4 s1 = (f32x4){0.f, 0.f, 0.f, 0.f};
      {
        const bf16* kbase = kk2 + (((size_t)b * 256 + ((n0 + wn0) >> 4)) << 10);
        bf16x8 b00 = *(const bf16x8*)(kbase + lane * 8);
        bf16x8 b01 = *(const bf16x8*)(kbase + 512 + lane * 8);
        bf16x8 b10 = *(const bf16x8*)(kbase + 1024 + lane * 8);
        bf16x8 b11 = *(const bf16x8*)(kbase + 1536 + lane * 8);
        s0 = __builtin_amdgcn_mfma_f32_16x16x32_bf16(qf0, b00, s0, 0, 0, 0);
        s0 = __builtin_amdgcn_mfma_f32_16x16x32_bf16(qf1, b01, s0, 0, 0, 0);
        s1 = __builtin_amdgcn_mfma_f32_16x16x32_bf16(qf0, b10, s1, 0, 0, 0);
        s1 = __builtin_amdgcn_mfma_f32_16x16x32_bf16(qf1, b11, s1, 0, 0, 0);
      }
      // branchless bias + exp2 (logits bounded; 2^x)
      #pragma unroll
      for (int nt = 0; nt < 2; nt++){
        int nl = wn0 + nt * 16 + l16;
        float axf = axs[nl];
        f32x4 sv = nt ? s1 : s0;
        #pragma unroll
        for (int r = 0; r < 4; r++){
          float gxr = axf + bxr[r];            // in [0, 23.7) (proved)
          int j0 = (int)gxr;                   // trunc == floor (gxr >= 0)
          float wx = gxr - (float)j0;
          float g0 = g[nl][j0], g1 = g[nl][j0 + 1];
          float bias = fmaf(wx, g1 - g0, g0);
          float e = fast_exp2(fmaf(sv[r], scale2, bias));
          s_runw[r] += e;
          ps[q16 * 4 + r][nl] = (bf16)e;
        }
      }
      // PV MFMA: A=ps (same-wave), fragment-major V — 3 contiguous 1KB reads
      {
        bf16x8 pa = *(const bf16x8*)&ps[l16][wn0 + q16 * 8];
        const bf16* vbase = vt2 + ((size_t)b * 128 + ((n0 + wn0) >> 5)) * 1536
                          + l16 * 32 + q16 * 8;
        #pragma unroll
        for (int ct = 0; ct < 3; ct++){
          bf16x8 vb = *(const bf16x8*)(vbase + ct * 512);
          oacc[ct] = __builtin_amdgcn_mfma_f32_16x16x32_bf16(pa, vb, oacc[ct], 0, 0, 0);
        }
      }
    }
    // deferred denominator reduce (once, not per chunk)
    #pragma unroll
    for (int r = 0; r < 4; r++){
      #pragma unroll
      for (int msk = 1; msk < 16; msk <<= 1)
        s_runw[r] += __shfl_xor(s_runw[r], msk);
    }
    // epilogue: cross-wave plain sums (scratch aliases g/axs)
    __syncthreads();
    float* ored = (float*)g;         // 64x48 f32 = 12288 <= 13312
    float* sred = axs;               // 64 floats
    #pragma unroll
    for (int ct = 0; ct < 3; ct++)
      #pragma unroll
      for (int r = 0; r < 4; r++)
        ored[(wid * 16 + q16 * 4 + r) * 48 + ct * 16 + l16] = oacc[ct][r];
    if (l16 == 0){
      #pragma unroll
      for (int r = 0; r < 4; r++) sred[wid * 16 + q16 * 4 + r] = s_runw[r];
    }
    __syncthreads();
    size_t obase = ((size_t)(b * 2 + kp) * Cch) * Nn;
    #pragma unroll
    for (int e = 0; e < 3; e++){
      int idx = tid + e * 256;         // 768 = 48c x 16m
      int c = idx >> 4, mm = idx & 15;
      float v = ored[mm * 48 + c] + ored[(16 + mm) * 48 + c]
              + ored[(32 + mm) * 48 + c] + ored[(48 + mm) * 48 + c];
      o_part[obase + (size_t)c * Nn + m0 + mm] = v;
    }
    if (tid < 16)
      s_part[(size_t)(b * 2 + kp) * Nn + m0 + tid] =
          sred[tid] + sred[16 + tid] + sred[32 + tid] + sred[48 + tid];
  } else {
    // ================= window attention path =================
    bf16 (*xs)[72]  = (bf16(*)[72])smem;                  // 9216 (later psw)
    bf16 (*wtt)[72] = (bf16(*)[72])(smem + 9216);         // 4608
    bf16 (*qs)[72]  = (bf16(*)[72])(smem + 13824);        // 9216
    bf16 (*vst)[72] = (bf16(*)[72])(smem + 23040);        // 2304
    float* bnsc = (float*)(smem + 25344);                 // 128
    float* bnsh = (float*)(smem + 25472);                 // 128 -> 25600
    bf16 (*psw)[72] = xs;   // overlay: xs dead after proj barrier

    int wb = blockIdx.x - 1024;
    int s = wb >> 7;
    int r7 = wb & 127;
    int b = r7 >> 6, wi = r7 & 63;
    for (int f = tid; f < 64 * 48; f += 256){
      int t = f & 63, c = f >> 6;
      int p = (s == 0) ? (((wi >> 3) * 8 + (t >> 3)) * 64 + (wi & 7) * 8 + (t & 7))
            : (s == 1) ? (t * 64 + wi) : (wi * 64 + t);
      xs[t][c] = (bf16)x[((size_t)(b * 48 + c)) * Nn + p];
    }
    for (int f = tid; f < 64 * 16; f += 256){
      int t = f >> 4, j = f & 15;
      xs[t][48 + j] = (bf16)0.f;
      qs[t][16 + j] = (bf16)0.f;
    }
    for (int f = tid; f < 32 * 64; f += 256){
      int o = f >> 6, c = f & 63;
      wtt[o][c] = (c < 48) ? (bf16)iw[(s * 32 + o) * 48 + c] : (bf16)0.f;
    }
    if (tid < 32){
      int ch = s * 32 + tid;
      float sc = bng[ch] * rsqrtf(bnv[ch] + 1e-5f);
      bnsc[tid] = sc;
      bnsh[tid] = (ib[ch] - bnm[ch]) * sc + bnb[ch];
    }
    __syncthreads();
    {
      bf16x8 a0 = *(const bf16x8*)&xs[wid * 16 + l16][q16 * 8];
      bf16x8 a1 = *(const bf16x8*)&xs[wid * 16 + l16][32 + q16 * 8];
      #pragma unroll
      for (int nt = 0; nt < 2; nt++){
        bf16x8 b0 = *(const bf16x8*)&wtt[nt * 16 + l16][q16 * 8];
        bf16x8 b1 = *(const bf16x8*)&wtt[nt * 16 + l16][32 + q16 * 8];
        f32x4 acc = (f32x4){0.f, 0.f, 0.f, 0.f};
        acc = __builtin_amdgcn_mfma_f32_16x16x32_bf16(a0, b0, acc, 0, 0, 0);
        acc = __builtin_amdgcn_mfma_f32_16x16x32_bf16(a1, b1, acc, 0, 0, 0);
        float scv = bnsc[nt * 16 + l16], shv = bnsh[nt * 16 + l16];
        #pragma unroll
        for (int r = 0; r < 4; r++){
          float v = fmaf(acc[r], scv, shv);
          int tok = wid * 16 + q16 * 4 + r;
          if (nt == 0) qs[tok][l16] = (bf16)v;       // C-layout: col=channel
          else         vst[l16][tok] = (bf16)v;      // transposed
        }
      }
    }
    __syncthreads();   // all waves done with xs -> safe to overlay psw
    f32x4 sreg[4];
    {
      bf16x8 aq = *(const bf16x8*)&qs[wid * 16 + l16][q16 * 8];
      #pragma unroll
      for (int nt = 0; nt < 4; nt++){
        bf16x8 bq = *(const bf16x8*)&qs[nt * 16 + l16][q16 * 8];
        f32x4 acc = (f32x4){0.f, 0.f, 0.f, 0.f};
        sreg[nt] = __builtin_amdgcn_mfma_f32_16x16x32_bf16(aq, bq, acc, 0, 0, 0);
      }
    }
    float rinv[4];
    #pragma unroll
    for (int r = 0; r < 4; r++){
      float mx = fmaxf(fmaxf(sreg[0][r], sreg[1][r]), fmaxf(sreg[2][r], sreg[3][r]));
      #pragma unroll
      for (int msk = 1; msk < 16; msk <<= 1) mx = fmaxf(mx, __shfl_xor(mx, msk));
      float sum = 0.f;
      #pragma unroll
      for (int nt = 0; nt < 4; nt++){
        float e = __expf(sreg[nt][r] - mx);
        sum += e;
        psw[wid * 16 + q16 * 4 + r][nt * 16 + l16] = (bf16)e;
      }
      #pragma unroll
      for (int msk = 1; msk < 16; msk <<= 1) sum += __shfl_xor(sum, msk);
      rinv[r] = 1.f / sum;
    }
    f32x4 oac = (f32x4){0.f, 0.f, 0.f, 0.f};
    {
      bf16x8 pa0 = *(const bf16x8*)&psw[wid * 16 + l16][q16 * 8];
      bf16x8 pa1 = *(const bf16x8*)&psw[wid * 16 + l16][32 + q16 * 8];
      bf16x8 vb0 = *(const bf16x8*)&vst[l16][q16 * 8];
      bf16x8 vb1 = *(const bf16x8*)&vst[l16][32 + q16 * 8];
      oac = __builtin_amdgcn_mfma_f32_16x16x32_bf16(pa0, vb0, oac, 0, 0, 0);
      oac = __builtin_amdgcn_mfma_f32_16x16x32_bf16(pa1, vb1, oac, 0, 0, 0);
    }
    #pragma unroll
    for (int r = 0; r < 4; r++){
      int tok = wid * 16 + q16 * 4 + r;
      int p = (s == 0) ? (((wi >> 3) * 8 + (tok >> 3)) * 64 + (wi & 7) * 8 + (tok & 7))
            : (s == 1) ? (tok * 64 + wi) : (wi * 64 + tok);
      wout[((size_t)(b * 48 + s * 16 + l16)) * Nn + p] = oac[r] * rinv[r];
    }
  }
}

// ---------------- K5: pout conv + split-K merge + 0.5/0.5 mix ----------------
// Original 1536-block channel-per-block form (R15's 128-block LDS variant
// regressed: half the CUs idle; win re-read is L2-absorbed anyway).
__global__ void k_final(const float* __restrict__ win, const float* __restrict__ pw,
                        const float* __restrict__ pb, const float* __restrict__ o_part,
                        const float* __restrict__ s_part, float* __restrict__ out){
  int chunk = blockIdx.x & 15;
  int o = (blockIdx.x >> 4) % Cch;
  int b = blockIdx.x / (16 * Cch);
  int p = chunk * 256 + threadIdx.x;
  float acc = pb[o];
  const float* ip = win + (b * Cch) * Nn + p;
  const float* wp = pw + o * Cch;
  #pragma unroll
  for (int c = 0; c < Cch; c++) acc += wp[c] * ip[c * Nn];
  float sden = s_part[(size_t)(b * 2) * Nn + p] + s_part[(size_t)(b * 2 + 1) * Nn + p];
  float odv = (o_part[((size_t)(b * 2) * Cch + o) * Nn + p]
             + o_part[((size_t)(b * 2 + 1) * Cch + o) * Nn + p]) / sden;
  out[(b * Cch + o) * Nn + p] = 0.5f * acc + 0.5f * odv;
}

extern "C" void kernel_launch(void* const* d_in, const int* in_sizes, int n_in,
                              void* d_out, int out_size, void* d_ws, size_t ws_size,
                              hipStream_t stream){
  const float* x   = (const float*)d_in[0];
  const float* Wq  = (const float*)d_in[1];
  const float* bq  = (const float*)d_in[2];
  const float* dww = (const float*)d_in[3];
  const float* dwb = (const float*)d_in[4];
  const float* lng = (const float*)d_in[5];
  const float* lnb = (const float*)d_in[6];
  const float* pww = (const float*)d_in[7];
  const float* Wk  = (const float*)d_in[8];
  const float* bk  = (const float*)d_in[9];
  const float* Wv  = (const float*)d_in[10];
  const float* bv  = (const float*)d_in[11];
  const float* iw  = (const float*)d_in[12];
  const float* ib  = (const float*)d_in[13];
  const float* bng = (const float*)d_in[14];
  const float* bnb = (const float*)d_in[15];
  const float* bnm = (const float*)d_in[16];
  const float* bnv = (const float*)d_in[17];
  const float* pw  = (const float*)d_in[18];
  const float* pb  = (const float*)d_in[19];
  const float* rpe = (const float*)d_in[20];

  // Workspace (f32-slot offsets). qnc aliases o_part[0,393216): qnc dead after
  // k_pos_kv, o_part written later by k_attn_win.
  float*    ws     = (float*)d_ws;
  float*    qnc    = ws;                    // [0,       393216)  dead after K2'
  float*    o_part = ws;                    // [0,       786432)
  float2*   axay   = (float2*)(ws + 802816);// 8192 float2 -> [802816, 819200)
  float*    wout   = ws + 819200;           // (B,C,N)     [819200, 1212416)
  bf16*     q_bf   = (bf16*)(ws + 1212416); // 524288 bf16 -> [1212416,1474560)
  bf16*     kk2    = (bf16*)(ws + 1474560); // 524288 bf16 -> [1474560,1736704)
  bf16*     vt2    = (bf16*)(ws + 1736704); // 393216 bf16 -> [1736704,1933312)
  float*    s_part = ws + 1933312;          // [1933312,1949696)
  unsigned* rpe2   = (unsigned*)(ws + 1949696); // 60216 dwords -> [1949696,2009912)
  float*    x_t    = ws + 2009912;          // (B,N,48) f32 -> [2009912,2403128) = 9.6 MB
  float*    out    = (float*)d_out;

  k_conv1x1 <<<Bsz * Cch * 16 + 193, 256, 0, stream>>>(x, Wq, bq, qnc, q_bf, x_t,
                                                       rpe, rpe2);
  k_pos_kv  <<<(Bsz * Nn) / 8, 512, 0, stream>>>(qnc, dww, dwb, lng, lnb, pww,
                                                 x_t, Wk, bk, Wv, bv,
                                                 kk2, vt2, axay);
  k_attn_win<<<Bsz * 512 + 384, 256, 0, stream>>>(q_bf, kk2, vt2, axay, rpe2,
                                                  o_part, s_part,
                                                  x, iw, ib, bng, bnb, bnm, bnv, wout);
  k_final   <<<Bsz * Cch * 16, 256, 0, stream>>>(wout, pw, pb, o_part,
                                                 s_part, out);
}